// Round 2
// baseline (426.098 us; speedup 1.0000x reference)
//
#include <hip/hip_runtime.h>

typedef unsigned short u16;
typedef __attribute__((ext_vector_type(4))) unsigned short u16x4;
typedef __attribute__((ext_vector_type(8))) unsigned short u16x8;
typedef __attribute__((ext_vector_type(8))) short s16x8;
typedef __attribute__((ext_vector_type(4))) float f32x4;

__device__ __forceinline__ u16 f2bf(float f) {
  unsigned int u = __float_as_uint(f);
  u += 0x7FFFu + ((u >> 16) & 1u);   // RNE
  return (u16)(u >> 16);
}
__device__ __forceinline__ float bf2f(u16 h) {
  return __uint_as_float(((unsigned int)h) << 16);
}

// ---------------- fp32 -> bf16 convert (x4 vectorized) ----------------
__global__ __launch_bounds__(256) void cvt_kernel(const float* __restrict__ src,
                                                  u16* __restrict__ dst, int n4) {
  int i = blockIdx.x * 256 + threadIdx.x;
  if (i >= n4) return;
  float4 v = reinterpret_cast<const float4*>(src)[i];
  u16x4 o;
  o.x = f2bf(v.x); o.y = f2bf(v.y); o.z = f2bf(v.z); o.w = f2bf(v.w);
  reinterpret_cast<u16x4*>(dst)[i] = o;
}

// all four 1024x1024 weights in one launch
__global__ __launch_bounds__(256) void cvt_w(const float* __restrict__ Wq,
                                             const float* __restrict__ Wk,
                                             const float* __restrict__ Wv,
                                             const float* __restrict__ Wo,
                                             u16* __restrict__ wbf, u16* __restrict__ wobf) {
  int blk = blockIdx.x;           // 0..4095
  int sel = blk >> 10;
  const float* src = (sel == 0) ? Wq : (sel == 1) ? Wk : (sel == 2) ? Wv : Wo;
  u16* dst = (sel < 3) ? (wbf + (size_t)sel * 1048576) : wobf;
  int i = (blk & 1023) * 256 + threadIdx.x;
  float4 v = reinterpret_cast<const float4*>(src)[i];
  u16x4 o;
  o.x = f2bf(v.x); o.y = f2bf(v.y); o.z = f2bf(v.z); o.w = f2bf(v.w);
  reinterpret_cast<u16x4*>(dst)[i] = o;
}

// ---------------- GEMM: C[m][n] = sum_k A[m][k] * B[n][k] (B^T input) ----------------
__device__ __forceinline__ void store_out(float* p, float v) { *p = v; }
__device__ __forceinline__ void store_out(u16* p, float v) { *p = f2bf(v); }

template <typename OutT>
__global__ __launch_bounds__(256) void gemm_bt(const u16* __restrict__ A,
                                               const u16* __restrict__ Bw,
                                               OutT* __restrict__ C, int N, int K) {
  __shared__ u16 As[128 * 32];
  __shared__ u16 Bs[128 * 32];
  const int tid = threadIdx.x;
  const int lane = tid & 63;
  const int wave = tid >> 6;
  const int wm = wave >> 1, wn = wave & 1;
  const int lh = lane & 15, quad = lane >> 4;
  const int m0 = blockIdx.y * 128, n0 = blockIdx.x * 128;

  f32x4 acc[4][4];
#pragma unroll
  for (int i = 0; i < 4; ++i)
#pragma unroll
    for (int j = 0; j < 4; ++j) { acc[i][j][0] = 0.f; acc[i][j][1] = 0.f; acc[i][j][2] = 0.f; acc[i][j][3] = 0.f; }

  const int c0 = tid, c1 = tid + 256;
  const int r0 = c0 >> 2, k0c = (c0 & 3) * 8;
  const int r1 = c1 >> 2, k1c = (c1 & 3) * 8;
  const int nkt = K >> 5;
  for (int kt = 0; kt < nkt; ++kt) {
    const int kb = kt * 32;
    u16x8 av0 = *reinterpret_cast<const u16x8*>(A + (size_t)(m0 + r0) * K + kb + k0c);
    u16x8 av1 = *reinterpret_cast<const u16x8*>(A + (size_t)(m0 + r1) * K + kb + k1c);
    u16x8 bv0 = *reinterpret_cast<const u16x8*>(Bw + (size_t)(n0 + r0) * K + kb + k0c);
    u16x8 bv1 = *reinterpret_cast<const u16x8*>(Bw + (size_t)(n0 + r1) * K + kb + k1c);
    __syncthreads();
    reinterpret_cast<u16x8*>(As)[c0] = av0;
    reinterpret_cast<u16x8*>(As)[c1] = av1;
    reinterpret_cast<u16x8*>(Bs)[c0] = bv0;
    reinterpret_cast<u16x8*>(Bs)[c1] = bv1;
    __syncthreads();
    s16x8 af[4], bf4[4];
#pragma unroll
    for (int mb = 0; mb < 4; ++mb)
      af[mb] = *reinterpret_cast<const s16x8*>(&As[(wm * 64 + mb * 16 + lh) * 32 + quad * 8]);
#pragma unroll
    for (int nb = 0; nb < 4; ++nb)
      bf4[nb] = *reinterpret_cast<const s16x8*>(&Bs[(wn * 64 + nb * 16 + lh) * 32 + quad * 8]);
#pragma unroll
    for (int mb = 0; mb < 4; ++mb)
#pragma unroll
      for (int nb = 0; nb < 4; ++nb)
        acc[mb][nb] = __builtin_amdgcn_mfma_f32_16x16x32_bf16(af[mb], bf4[nb], acc[mb][nb], 0, 0, 0);
  }
#pragma unroll
  for (int mb = 0; mb < 4; ++mb)
#pragma unroll
    for (int nb = 0; nb < 4; ++nb) {
      const int col = n0 + wn * 64 + nb * 16 + lh;
#pragma unroll
      for (int r = 0; r < 4; ++r) {
        const int row = m0 + wm * 64 + mb * 16 + quad * 4 + r;
        store_out(&C[(size_t)row * N + col], acc[mb][nb][r]);
      }
    }
}

// ---------------- RoPE + pre-scale: raw QKV -> Qs(q/8), Q2s(0.0125 q^2), K, K^2 ----------------
__global__ __launch_bounds__(256) void rope_kernel(const u16* __restrict__ raw,
                                                   u16* __restrict__ Qs, u16* __restrict__ Q2s,
                                                   u16* __restrict__ Kb, u16* __restrict__ K2b) {
  int idx = blockIdx.x * 256 + threadIdx.x;  // 0 .. 4194303
  int which = idx >> 21;                     // 0 = Q, 1 = K
  int id = idx & 0x1FFFFF;
  int d = id & 31;
  int s = (id >> 5) & 2047;
  int bh = id >> 16;                         // b*16 + h
  int b = bh >> 4;
  int h = bh & 15;
  const u16* r = raw + (size_t)(b * 2048 + s) * 3072 + which * 1024 + h * 64 + d;
  float v1 = bf2f(r[0]);
  float v2 = bf2f(r[32]);
  float invf = __expf((float)d * -0.2878231366f);  // 10000^(-d/32)
  float ang = (float)s * invf;
  float sv, cv;
  __sincosf(ang, &sv, &cv);
  float e0 = v1 * cv - v2 * sv;
  float e1 = v2 * cv + v1 * sv;
  size_t ofs = (size_t)(bh * 2048 + s) * 64 + d;
  if (which == 0) {
    Qs[ofs]       = f2bf(e0 * 0.125f);
    Qs[ofs + 32]  = f2bf(e1 * 0.125f);
    Q2s[ofs]      = f2bf(e0 * e0 * 0.0125f);
    Q2s[ofs + 32] = f2bf(e1 * e1 * 0.0125f);
  } else {
    Kb[ofs]       = f2bf(e0);
    Kb[ofs + 32]  = f2bf(e1);
    K2b[ofs]      = f2bf(e0 * e0);
    K2b[ofs + 32] = f2bf(e1 * e1);
  }
}

// ---------------- V transpose: raw V cols -> Vt (B,H,64,S) bf16 ----------------
__global__ __launch_bounds__(256) void transpose_v(const u16* __restrict__ raw,
                                                   u16* __restrict__ Vt) {
  int st = blockIdx.x, bh = blockIdx.y;
  int b = bh >> 4, h = bh & 15;
  __shared__ u16 tile[64 * 72];
  int tid = threadIdx.x;
#pragma unroll
  for (int it = 0; it < 4; ++it) {
    int c = it * 256 + tid;
    int sr = c >> 4, d4 = c & 15;
    u16x4 v = *reinterpret_cast<const u16x4*>(
        raw + (size_t)(b * 2048 + st * 64 + sr) * 3072 + 2048 + h * 64 + d4 * 4);
    *reinterpret_cast<u16x4*>(&tile[sr * 72 + d4 * 4]) = v;
  }
  __syncthreads();
#pragma unroll
  for (int it = 0; it < 4; ++it) {
    int c = it * 256 + tid;
    int dd = c >> 4, s4 = c & 15;
    u16x4 v;
#pragma unroll
    for (int j = 0; j < 4; ++j) v[j] = tile[(s4 * 4 + j) * 72 + dd];
    *reinterpret_cast<u16x4*>(Vt + (size_t)(bh * 64 + dd) * 2048 + st * 64 + s4 * 4) = v;
  }
}

// ---------------- flash-style causal amplified attention ----------------
// 1 wave per block, 16 Q rows per wave; grid (128, 32), qtile = 127 - bx (long blocks first).
__global__ __launch_bounds__(64) void attn_kernel(const u16* __restrict__ Qs,
                                                  const u16* __restrict__ Q2s,
                                                  const u16* __restrict__ Kb,
                                                  const u16* __restrict__ K2b,
                                                  const u16* __restrict__ Vt,
                                                  const float* __restrict__ gate,
                                                  u16* __restrict__ attn) {
  const int qtile = 127 - (int)blockIdx.x;
  const int bh = blockIdx.y;
  const int lane = threadIdx.x & 63;
  const int lh = lane & 15, quad = lane >> 4;
  const int b = bh >> 4, h = bh & 15;
  __shared__ u16 myP[16 * 72];
  const int qrow0 = qtile * 16;

  // Q fragments (A-layout): m = lh, k = kk*32 + quad*8 + j ; pre-scaled in memory
  s16x8 qf[2], q2f[2];
  {
    const size_t qoff = (size_t)(bh * 2048 + qrow0 + lh) * 64 + quad * 8;
    qf[0]  = *reinterpret_cast<const s16x8*>(Qs + qoff);
    qf[1]  = *reinterpret_cast<const s16x8*>(Qs + qoff + 32);
    q2f[0] = *reinterpret_cast<const s16x8*>(Q2s + qoff);
    q2f[1] = *reinterpret_cast<const s16x8*>(Q2s + qoff + 32);
  }

  float m_st[4], l_st[4];
  f32x4 oacc[4];
#pragma unroll
  for (int r = 0; r < 4; ++r) { m_st[r] = -1e30f; l_st[r] = 0.f; }
#pragma unroll
  for (int nb = 0; nb < 4; ++nb) { oacc[nb][0] = 0.f; oacc[nb][1] = 0.f; oacc[nb][2] = 0.f; oacc[nb][3] = 0.f; }
  float gw[4];
#pragma unroll
  for (int nb = 0; nb < 4; ++nb) gw[nb] = gate[nb * 16 + lh];

  const int ktmax = qtile >> 2;
  for (int kt = 0; kt <= ktmax; ++kt) {
    f32x4 sacc[4];
#pragma unroll
    for (int nb = 0; nb < 4; ++nb) { sacc[nb][0] = 0.f; sacc[nb][1] = 0.f; sacc[nb][2] = 0.f; sacc[nb][3] = 0.f; }
    const u16* kbase  = Kb  + (size_t)(bh * 2048 + kt * 64 + lh) * 64 + quad * 8;
    const u16* k2base = K2b + (size_t)(bh * 2048 + kt * 64 + lh) * 64 + quad * 8;
#pragma unroll
    for (int nb = 0; nb < 4; ++nb) {
#pragma unroll
      for (int kk = 0; kk < 2; ++kk) {
        s16x8 kf  = *reinterpret_cast<const s16x8*>(kbase  + nb * 1024 + kk * 32);
        s16x8 k2f = *reinterpret_cast<const s16x8*>(k2base + nb * 1024 + kk * 32);
        sacc[nb] = __builtin_amdgcn_mfma_f32_16x16x32_bf16(qf[kk],  kf,  sacc[nb], 0, 0, 0);
        sacc[nb] = __builtin_amdgcn_mfma_f32_16x16x32_bf16(q2f[kk], k2f, sacc[nb], 0, 0, 0);
      }
    }
    // prefetch V fragments (B-layout) so global latency overlaps the softmax VALU chain
    s16x8 vf[2][4];
#pragma unroll
    for (int kk = 0; kk < 2; ++kk)
#pragma unroll
      for (int nb = 0; nb < 4; ++nb)
        vf[kk][nb] = *reinterpret_cast<const s16x8*>(
            Vt + (size_t)(bh * 64 + nb * 16 + lh) * 2048 + kt * 64 + kk * 32 + quad * 8);

    if (kt == ktmax) {  // causal mask on the (partial) diagonal tile
#pragma unroll
      for (int nb = 0; nb < 4; ++nb) {
        const int colg = kt * 64 + nb * 16 + lh;
#pragma unroll
        for (int r = 0; r < 4; ++r) {
          const int rowg = qrow0 + quad * 4 + r;
          if (colg > rowg) sacc[nb][r] = -1e9f;
        }
      }
    }
    // online softmax (rows live across 16 lanes of each quad)
    float mnew[4];
#pragma unroll
    for (int r = 0; r < 4; ++r) {
      float mx = fmaxf(fmaxf(sacc[0][r], sacc[1][r]), fmaxf(sacc[2][r], sacc[3][r]));
#pragma unroll
      for (int off = 1; off < 16; off <<= 1) mx = fmaxf(mx, __shfl_xor(mx, off));
      mnew[r] = fmaxf(m_st[r], mx);
    }
    float p[4][4];
#pragma unroll
    for (int nb = 0; nb < 4; ++nb)
#pragma unroll
      for (int r = 0; r < 4; ++r) p[nb][r] = __expf(sacc[nb][r] - mnew[r]);
#pragma unroll
    for (int r = 0; r < 4; ++r) {
      float rs = p[0][r] + p[1][r] + p[2][r] + p[3][r];
#pragma unroll
      for (int off = 1; off < 16; off <<= 1) rs += __shfl_xor(rs, off);
      float alpha = __expf(m_st[r] - mnew[r]);
      l_st[r] = l_st[r] * alpha + rs;
      m_st[r] = mnew[r];
#pragma unroll
      for (int nb = 0; nb < 4; ++nb) oacc[nb][r] *= alpha;
    }
    // P: C-layout -> LDS -> A-layout (wave-private, no barrier)
#pragma unroll
    for (int nb = 0; nb < 4; ++nb)
#pragma unroll
      for (int r = 0; r < 4; ++r)
        myP[(quad * 4 + r) * 72 + nb * 16 + lh] = f2bf(p[nb][r]);
#pragma unroll
    for (int kk = 0; kk < 2; ++kk) {
      s16x8 pf = *reinterpret_cast<const s16x8*>(&myP[lh * 72 + kk * 32 + quad * 8]);
#pragma unroll
      for (int nb = 0; nb < 4; ++nb)
        oacc[nb] = __builtin_amdgcn_mfma_f32_16x16x32_bf16(pf, vf[kk][nb], oacc[nb], 0, 0, 0);
    }
  }
  // finalize: o/l, epilogue o + 0.05*o^2*g[d] (out2==out1 identity)
  float invl[4];
#pragma unroll
  for (int r = 0; r < 4; ++r) invl[r] = 1.0f / l_st[r];
#pragma unroll
  for (int nb = 0; nb < 4; ++nb)
#pragma unroll
    for (int r = 0; r < 4; ++r) {
      float o = oacc[nb][r] * invl[r];
      float val = o + 0.05f * o * o * gw[nb];
      const int rows = qrow0 + quad * 4 + r;
      attn[(size_t)(b * 2048 + rows) * 1024 + h * 64 + nb * 16 + lh] = f2bf(val);
    }
}

extern "C" void kernel_launch(void* const* d_in, const int* in_sizes, int n_in,
                              void* d_out, int out_size, void* d_ws, size_t ws_size,
                              hipStream_t stream) {
  (void)in_sizes; (void)n_in; (void)out_size; (void)ws_size;
  const float* x    = (const float*)d_in[0];
  const float* Wq   = (const float*)d_in[1];
  const float* Wk   = (const float*)d_in[2];
  const float* Wv   = (const float*)d_in[3];
  const float* Wo   = (const float*)d_in[4];
  const float* gate = (const float*)d_in[5];

  u16* ws    = (u16*)d_ws;
  u16* xbf   = ws;                    // 4096x1024 (dead after QKV gemm)
  u16* wbf   = xbf + 4194304;         // 3072x1024 (Wq|Wk|Wv rows)
  u16* wobf  = wbf + 3145728;         // 1024x1024
  u16* raw   = wobf + 1048576;        // 4096x3072 QKV gemm out (dead after rope+transpose)
  u16* Qsb   = raw + 12582912;        // (B,H,S,64) q/8
  u16* Kbb   = Qsb + 4194304;         // (B,H,S,64)
  u16* K2bb  = Kbb + 4194304;         // (B,H,S,64)
  u16* Vtb   = K2bb + 4194304;        // (B,H,64,S)
  u16* Q2sb  = xbf;                   // alias: written by rope (after gemm)
  u16* attnb = raw;                   // alias: written by attn (after rope/transpose)

  cvt_kernel<<<4096, 256, 0, stream>>>(x, xbf, 1048576);
  cvt_w<<<4096, 256, 0, stream>>>(Wq, Wk, Wv, Wo, wbf, wobf);

  gemm_bt<u16><<<dim3(24, 32), 256, 0, stream>>>(xbf, wbf, raw, 3072, 1024);
  rope_kernel<<<16384, 256, 0, stream>>>(raw, Qsb, Q2sb, Kbb, K2bb);
  transpose_v<<<dim3(32, 32), 256, 0, stream>>>(raw, Vtb);
  attn_kernel<<<dim3(128, 32), 64, 0, stream>>>(Qsb, Q2sb, Kbb, K2bb, Vtb, gate, attnb);
  gemm_bt<float><<<dim3(8, 32), 256, 0, stream>>>(attnb, wobf, (float*)d_out, 1024, 1024);
}

// Round 4
// 391.418 us; speedup vs baseline: 1.0886x; 1.0886x over previous
//
#include <hip/hip_runtime.h>

typedef unsigned short u16;
typedef __attribute__((ext_vector_type(4))) unsigned short u16x4;
typedef __attribute__((ext_vector_type(8))) unsigned short u16x8;
typedef __attribute__((ext_vector_type(8))) short s16x8;
typedef __attribute__((ext_vector_type(4))) float f32x4;

__device__ __forceinline__ u16 f2bf(float f) {
  unsigned int u = __float_as_uint(f);
  u += 0x7FFFu + ((u >> 16) & 1u);   // RNE
  return (u16)(u >> 16);
}
__device__ __forceinline__ float bf2f(u16 h) {
  return __uint_as_float(((unsigned int)h) << 16);
}

// async global->LDS, 16B per lane; HW semantics: base = lane0's lds ptr, lane i
// writes base + i*16B. Passing &base[lane*8] (u16) matches that exactly.
__device__ __forceinline__ void gload_lds16(const u16* g, u16* l) {
  __builtin_amdgcn_global_load_lds(
      (const __attribute__((address_space(1))) unsigned int*)(g),
      (__attribute__((address_space(3))) unsigned int*)(l), 16, 0, 0);
}

// ---------------- fp32 -> bf16 convert (x4 vectorized) ----------------
__global__ __launch_bounds__(256) void cvt_kernel(const float* __restrict__ src,
                                                  u16* __restrict__ dst, int n4) {
  int i = blockIdx.x * 256 + threadIdx.x;
  if (i >= n4) return;
  float4 v = reinterpret_cast<const float4*>(src)[i];
  u16x4 o;
  o.x = f2bf(v.x); o.y = f2bf(v.y); o.z = f2bf(v.z); o.w = f2bf(v.w);
  reinterpret_cast<u16x4*>(dst)[i] = o;
}

// all four 1024x1024 weights in one launch
__global__ __launch_bounds__(256) void cvt_w(const float* __restrict__ Wq,
                                             const float* __restrict__ Wk,
                                             const float* __restrict__ Wv,
                                             const float* __restrict__ Wo,
                                             u16* __restrict__ wbf, u16* __restrict__ wobf) {
  int blk = blockIdx.x;           // 0..4095
  int sel = blk >> 10;
  const float* src = (sel == 0) ? Wq : (sel == 1) ? Wk : (sel == 2) ? Wv : Wo;
  u16* dst = (sel < 3) ? (wbf + (size_t)sel * 1048576) : wobf;
  int i = (blk & 1023) * 256 + threadIdx.x;
  float4 v = reinterpret_cast<const float4*>(src)[i];
  u16x4 o;
  o.x = f2bf(v.x); o.y = f2bf(v.y); o.z = f2bf(v.z); o.w = f2bf(v.w);
  reinterpret_cast<u16x4*>(dst)[i] = o;
}

// ---------------- GEMM: C[m][n] = sum_k A[m][k] * B[n][k] (B^T input) ----------------
// 128x128 tile, BK=32, global_load_lds staging. Chunk c = 16 rows x 32 cols = 512 u16,
// packed at c*512 + lane*8 (lane's 16B slice = its own A/B fragment slice).
__device__ __forceinline__ void store_out(float* p, float v) { *p = v; }
__device__ __forceinline__ void store_out(u16* p, float v) { *p = f2bf(v); }

template <typename OutT>
__global__ __launch_bounds__(256) void gemm_bt(const u16* __restrict__ A,
                                               const u16* __restrict__ Bw,
                                               OutT* __restrict__ C, int N, int K) {
  __shared__ u16 As[4096];
  __shared__ u16 Bs[4096];
  const int tid = threadIdx.x;
  const int lane = tid & 63;
  const int wave = tid >> 6;
  const int wm = wave >> 1, wn = wave & 1;
  const int lh = lane & 15, quad = lane >> 4;
  const int q8 = quad * 8;
  const int m0 = blockIdx.y * 128, n0 = blockIdx.x * 128;

  f32x4 acc[4][4];
#pragma unroll
  for (int i = 0; i < 4; ++i)
#pragma unroll
    for (int j = 0; j < 4; ++j) { acc[i][j][0] = 0.f; acc[i][j][1] = 0.f; acc[i][j][2] = 0.f; acc[i][j][3] = 0.f; }

  const int nkt = K >> 5;
  for (int kt = 0; kt < nkt; ++kt) {
    const int kb = kt * 32;
    __syncthreads();  // prior tile's LDS reads done
#pragma unroll
    for (int i = 0; i < 4; ++i) {
      const int c = wave * 4 + i;  // 0..15 : 0-7 = A chunks, 8-15 = B chunks
      if (c < 8) {
        gload_lds16(A + (size_t)(m0 + c * 16 + lh) * K + kb + q8, &As[c * 512 + lane * 8]);
      } else {
        const int rb = c - 8;
        gload_lds16(Bw + (size_t)(n0 + rb * 16 + lh) * K + kb + q8, &Bs[rb * 512 + lane * 8]);
      }
    }
    __syncthreads();  // drains DMA (vmcnt(0) before s_barrier), staged tile visible
    s16x8 af[4], bf4[4];
#pragma unroll
    for (int mb = 0; mb < 4; ++mb)
      af[mb] = *reinterpret_cast<const s16x8*>(&As[(wm * 4 + mb) * 512 + lane * 8]);
#pragma unroll
    for (int nb = 0; nb < 4; ++nb)
      bf4[nb] = *reinterpret_cast<const s16x8*>(&Bs[(wn * 4 + nb) * 512 + lane * 8]);
#pragma unroll
    for (int mb = 0; mb < 4; ++mb)
#pragma unroll
      for (int nb = 0; nb < 4; ++nb)
        acc[mb][nb] = __builtin_amdgcn_mfma_f32_16x16x32_bf16(af[mb], bf4[nb], acc[mb][nb], 0, 0, 0);
  }
#pragma unroll
  for (int mb = 0; mb < 4; ++mb)
#pragma unroll
    for (int nb = 0; nb < 4; ++nb) {
      const int col = n0 + wn * 64 + nb * 16 + lh;
#pragma unroll
      for (int r = 0; r < 4; ++r) {
        const int row = m0 + wm * 64 + mb * 16 + quad * 4 + r;
        store_out(&C[(size_t)row * N + col], acc[mb][nb][r]);
      }
    }
}

// ---------------- RoPE + pre-scale: raw QKV -> Qs(q/8), Q2s(0.0125 q^2), K, K^2 ----------------
__global__ __launch_bounds__(256) void rope_kernel(const u16* __restrict__ raw,
                                                   u16* __restrict__ Qs, u16* __restrict__ Q2s,
                                                   u16* __restrict__ Kb, u16* __restrict__ K2b) {
  int idx = blockIdx.x * 256 + threadIdx.x;  // 0 .. 4194303
  int which = idx >> 21;                     // 0 = Q, 1 = K
  int id = idx & 0x1FFFFF;
  int d = id & 31;
  int s = (id >> 5) & 2047;
  int bh = id >> 16;                         // b*16 + h
  int b = bh >> 4;
  int h = bh & 15;
  const u16* r = raw + (size_t)(b * 2048 + s) * 3072 + which * 1024 + h * 64 + d;
  float v1 = bf2f(r[0]);
  float v2 = bf2f(r[32]);
  float invf = __expf((float)d * -0.2878231366f);  // 10000^(-d/32)
  float ang = (float)s * invf;
  float sv, cv;
  __sincosf(ang, &sv, &cv);
  float e0 = v1 * cv - v2 * sv;
  float e1 = v2 * cv + v1 * sv;
  size_t ofs = (size_t)(bh * 2048 + s) * 64 + d;
  if (which == 0) {
    Qs[ofs]       = f2bf(e0 * 0.125f);
    Qs[ofs + 32]  = f2bf(e1 * 0.125f);
    Q2s[ofs]      = f2bf(e0 * e0 * 0.0125f);
    Q2s[ofs + 32] = f2bf(e1 * e1 * 0.0125f);
  } else {
    Kb[ofs]       = f2bf(e0);
    Kb[ofs + 32]  = f2bf(e1);
    K2b[ofs]      = f2bf(e0 * e0);
    K2b[ofs + 32] = f2bf(e1 * e1);
  }
}

// ---------------- V transpose: raw V cols -> Vt (B,H,64,S) bf16 ----------------
__global__ __launch_bounds__(256) void transpose_v(const u16* __restrict__ raw,
                                                   u16* __restrict__ Vt) {
  int st = blockIdx.x, bh = blockIdx.y;
  int b = bh >> 4, h = bh & 15;
  __shared__ u16 tile[64 * 72];
  int tid = threadIdx.x;
#pragma unroll
  for (int it = 0; it < 4; ++it) {
    int c = it * 256 + tid;
    int sr = c >> 4, d4 = c & 15;
    u16x4 v = *reinterpret_cast<const u16x4*>(
        raw + (size_t)(b * 2048 + st * 64 + sr) * 3072 + 2048 + h * 64 + d4 * 4);
    *reinterpret_cast<u16x4*>(&tile[sr * 72 + d4 * 4]) = v;
  }
  __syncthreads();
#pragma unroll
  for (int it = 0; it < 4; ++it) {
    int c = it * 256 + tid;
    int dd = c >> 4, s4 = c & 15;
    u16x4 v;
#pragma unroll
    for (int j = 0; j < 4; ++j) v[j] = tile[(s4 * 4 + j) * 72 + dd];
    *reinterpret_cast<u16x4*>(Vt + (size_t)(bh * 64 + dd) * 2048 + st * 64 + s4 * 4) = v;
  }
}

// ---------------- flash-style causal amplified attention ----------------
// 256 thr = 4 waves per block, 64 Q rows; grid (32, 32), qt = 31 - bx (long blocks first).
// K / K^2 tiles double-buffered in LDS via async global_load_lds; chunks packed at
// stride 512 u16 (64 lanes x 16B). V prefetched per-wave from global (L1-shared).
__global__ __launch_bounds__(256) void attn_kernel(const u16* __restrict__ Qs,
                                                   const u16* __restrict__ Q2s,
                                                   const u16* __restrict__ Kb,
                                                   const u16* __restrict__ K2b,
                                                   const u16* __restrict__ Vt,
                                                   const float* __restrict__ gate,
                                                   u16* __restrict__ attn) {
  const int qt = 31 - (int)blockIdx.x;
  const int bh = blockIdx.y;
  const int tid = threadIdx.x, lane = tid & 63, wave = tid >> 6;
  const int lh = lane & 15, quad = lane >> 4;
  const int b = bh >> 4, h = bh & 15;
  __shared__ u16 stageS[2][8192];   // [K chunks: 0..4095 | K2 chunks: 4096..8191], 512 u16/chunk
  __shared__ u16 Pbuf[4][16 * 72];
  u16* myP = &Pbuf[wave][0];
  const int qrow0 = qt * 64 + wave * 16;
  const int q8 = quad * 8;

  // stage K/K2 tile kt; chunk c: t=c>>3 (0=K,1=K2), f=c&7 = kk*4+nb
  auto do_stage = [&](int buf, int kt) {
#pragma unroll
    for (int i = 0; i < 4; ++i) {
      const int c = wave * 4 + i;   // 0..15
      const int t = c >> 3, f = c & 7, kk = f >> 2, nb = f & 3;
      const u16* src = (t ? K2b : Kb) +
          (size_t)(bh * 2048 + kt * 64 + nb * 16 + lh) * 64 + kk * 32 + q8;
      gload_lds16(src, &stageS[buf][t * 4096 + f * 512 + lane * 8]);
    }
  };

  // Q fragments (A-layout): m = lh, k = kk*32 + quad*8 + j ; pre-scaled in memory
  s16x8 qf[2], q2f[2];
  {
    const size_t qoff = (size_t)(bh * 2048 + qrow0 + lh) * 64 + q8;
    qf[0]  = *reinterpret_cast<const s16x8*>(Qs + qoff);
    qf[1]  = *reinterpret_cast<const s16x8*>(Qs + qoff + 32);
    q2f[0] = *reinterpret_cast<const s16x8*>(Q2s + qoff);
    q2f[1] = *reinterpret_cast<const s16x8*>(Q2s + qoff + 32);
  }

  float m_st[4], l_st[4];
  f32x4 oacc[4];
#pragma unroll
  for (int r = 0; r < 4; ++r) { m_st[r] = -1e30f; l_st[r] = 0.f; }
#pragma unroll
  for (int nb = 0; nb < 4; ++nb) { oacc[nb][0] = 0.f; oacc[nb][1] = 0.f; oacc[nb][2] = 0.f; oacc[nb][3] = 0.f; }
  float gw[4];
#pragma unroll
  for (int nb = 0; nb < 4; ++nb) gw[nb] = gate[nb * 16 + lh];

  do_stage(0, 0);
  __syncthreads();  // drain DMA for tile 0

  const int ktmax = qt;
  for (int kt = 0; kt <= ktmax; ++kt) {
    const int p = kt & 1;
    if (kt < ktmax) do_stage(1 - p, kt + 1);  // async prefetch, drained at end barrier

    // QK^T + lambda (Q^2)(K^2)^T from LDS
    f32x4 sacc[4];
#pragma unroll
    for (int nb = 0; nb < 4; ++nb) { sacc[nb][0] = 0.f; sacc[nb][1] = 0.f; sacc[nb][2] = 0.f; sacc[nb][3] = 0.f; }
    const u16* Ks = stageS[p];
#pragma unroll
    for (int nb = 0; nb < 4; ++nb)
#pragma unroll
      for (int kk = 0; kk < 2; ++kk) {
        s16x8 kf  = *reinterpret_cast<const s16x8*>(&Ks[(kk * 4 + nb) * 512 + lane * 8]);
        s16x8 k2f = *reinterpret_cast<const s16x8*>(&Ks[4096 + (kk * 4 + nb) * 512 + lane * 8]);
        sacc[nb] = __builtin_amdgcn_mfma_f32_16x16x32_bf16(qf[kk],  kf,  sacc[nb], 0, 0, 0);
        sacc[nb] = __builtin_amdgcn_mfma_f32_16x16x32_bf16(q2f[kk], k2f, sacc[nb], 0, 0, 0);
      }
    // V prefetch (global; latency hides under softmax)
    s16x8 vf[2][4];
#pragma unroll
    for (int kk = 0; kk < 2; ++kk)
#pragma unroll
      for (int nb = 0; nb < 4; ++nb)
        vf[kk][nb] = *reinterpret_cast<const s16x8*>(
            Vt + (size_t)(bh * 64 + nb * 16 + lh) * 2048 + kt * 64 + kk * 32 + q8);

    if (kt == ktmax) {  // causal mask on the diagonal tile
#pragma unroll
      for (int nb = 0; nb < 4; ++nb) {
        const int colg = kt * 64 + nb * 16 + lh;
#pragma unroll
        for (int r = 0; r < 4; ++r) {
          const int rowg = qrow0 + quad * 4 + r;
          if (colg > rowg) sacc[nb][r] = -1e9f;
        }
      }
    }
    // online softmax (rows live across 16 lanes of each quad)
    float mnew[4];
#pragma unroll
    for (int r = 0; r < 4; ++r) {
      float mx = fmaxf(fmaxf(sacc[0][r], sacc[1][r]), fmaxf(sacc[2][r], sacc[3][r]));
#pragma unroll
      for (int off = 1; off < 16; off <<= 1) mx = fmaxf(mx, __shfl_xor(mx, off));
      mnew[r] = fmaxf(m_st[r], mx);
    }
    float p4[4][4];
#pragma unroll
    for (int nb = 0; nb < 4; ++nb)
#pragma unroll
      for (int r = 0; r < 4; ++r) p4[nb][r] = __expf(sacc[nb][r] - mnew[r]);
#pragma unroll
    for (int r = 0; r < 4; ++r) {
      float rs = p4[0][r] + p4[1][r] + p4[2][r] + p4[3][r];
#pragma unroll
      for (int off = 1; off < 16; off <<= 1) rs += __shfl_xor(rs, off);
      float alpha = __expf(m_st[r] - mnew[r]);
      l_st[r] = l_st[r] * alpha + rs;
      m_st[r] = mnew[r];
#pragma unroll
      for (int nb = 0; nb < 4; ++nb) oacc[nb][r] *= alpha;
    }
    // P: C-layout -> LDS -> A-layout (wave-private, no barrier)
#pragma unroll
    for (int nb = 0; nb < 4; ++nb)
#pragma unroll
      for (int r = 0; r < 4; ++r)
        myP[(quad * 4 + r) * 72 + nb * 16 + lh] = f2bf(p4[nb][r]);
#pragma unroll
    for (int kk = 0; kk < 2; ++kk) {
      s16x8 pf = *reinterpret_cast<const s16x8*>(&myP[lh * 72 + kk * 32 + q8]);
#pragma unroll
      for (int nb = 0; nb < 4; ++nb)
        oacc[nb] = __builtin_amdgcn_mfma_f32_16x16x32_bf16(pf, vf[kk][nb], oacc[nb], 0, 0, 0);
    }
    __syncthreads();  // all waves done reading stageS[p]; prefetch for kt+1 drained
  }
  // finalize: o/l, epilogue o + 0.05*o^2*g[d] (out2==out1 identity)
  float invl[4];
#pragma unroll
  for (int r = 0; r < 4; ++r) invl[r] = 1.0f / l_st[r];
#pragma unroll
  for (int nb = 0; nb < 4; ++nb)
#pragma unroll
    for (int r = 0; r < 4; ++r) {
      float o = oacc[nb][r] * invl[r];
      float val = o + 0.05f * o * o * gw[nb];
      const int rows = qrow0 + quad * 4 + r;
      attn[(size_t)(b * 2048 + rows) * 1024 + h * 64 + nb * 16 + lh] = f2bf(val);
    }
}

extern "C" void kernel_launch(void* const* d_in, const int* in_sizes, int n_in,
                              void* d_out, int out_size, void* d_ws, size_t ws_size,
                              hipStream_t stream) {
  (void)in_sizes; (void)n_in; (void)out_size; (void)ws_size;
  const float* x    = (const float*)d_in[0];
  const float* Wq   = (const float*)d_in[1];
  const float* Wk   = (const float*)d_in[2];
  const float* Wv   = (const float*)d_in[3];
  const float* Wo   = (const float*)d_in[4];
  const float* gate = (const float*)d_in[5];

  u16* ws    = (u16*)d_ws;
  u16* xbf   = ws;                    // 4096x1024 (dead after QKV gemm)
  u16* wbf   = xbf + 4194304;         // 3072x1024 (Wq|Wk|Wv rows)
  u16* wobf  = wbf + 3145728;         // 1024x1024
  u16* raw   = wobf + 1048576;        // 4096x3072 QKV gemm out (dead after rope+transpose)
  u16* Qsb   = raw + 12582912;        // (B,H,S,64) q/8
  u16* Kbb   = Qsb + 4194304;         // (B,H,S,64)
  u16* K2bb  = Kbb + 4194304;         // (B,H,S,64)
  u16* Vtb   = K2bb + 4194304;        // (B,H,64,S)
  u16* Q2sb  = xbf;                   // alias: written by rope (after gemm)
  u16* attnb = raw;                   // alias: written by attn (after rope/transpose)

  cvt_kernel<<<4096, 256, 0, stream>>>(x, xbf, 1048576);
  cvt_w<<<4096, 256, 0, stream>>>(Wq, Wk, Wv, Wo, wbf, wobf);

  gemm_bt<u16><<<dim3(24, 32), 256, 0, stream>>>(xbf, wbf, raw, 3072, 1024);
  rope_kernel<<<16384, 256, 0, stream>>>(raw, Qsb, Q2sb, Kbb, K2bb);
  transpose_v<<<dim3(32, 32), 256, 0, stream>>>(raw, Vtb);
  attn_kernel<<<dim3(32, 32), 256, 0, stream>>>(Qsb, Q2sb, Kbb, K2bb, Vtb, gate, attnb);
  gemm_bt<float><<<dim3(8, 32), 256, 0, stream>>>(attnb, wobf, (float*)d_out, 1024, 1024);
}

// Round 5
// 274.030 us; speedup vs baseline: 1.5549x; 1.4284x over previous
//
#include <hip/hip_runtime.h>

typedef unsigned short u16;
typedef __attribute__((ext_vector_type(4))) unsigned short u16x4;
typedef __attribute__((ext_vector_type(8))) unsigned short u16x8;
typedef __attribute__((ext_vector_type(8))) short s16x8;
typedef __attribute__((ext_vector_type(4))) float f32x4;

__device__ __forceinline__ u16 f2bf(float f) {
  unsigned int u = __float_as_uint(f);
  u += 0x7FFFu + ((u >> 16) & 1u);   // RNE
  return (u16)(u >> 16);
}
__device__ __forceinline__ float bf2f(u16 h) {
  return __uint_as_float(((unsigned int)h) << 16);
}

// async global->LDS, 16B per lane; base = lane0's lds ptr, lane i writes base+i*16B.
__device__ __forceinline__ void gload_lds16(const u16* g, u16* l) {
  __builtin_amdgcn_global_load_lds(
      (const __attribute__((address_space(1))) unsigned int*)(g),
      (__attribute__((address_space(3))) unsigned int*)(l), 16, 0, 0);
}

// ---------------- fp32 -> bf16 convert (x4 vectorized) ----------------
__global__ __launch_bounds__(256) void cvt_kernel(const float* __restrict__ src,
                                                  u16* __restrict__ dst, int n4) {
  int i = blockIdx.x * 256 + threadIdx.x;
  if (i >= n4) return;
  float4 v = reinterpret_cast<const float4*>(src)[i];
  u16x4 o;
  o.x = f2bf(v.x); o.y = f2bf(v.y); o.z = f2bf(v.z); o.w = f2bf(v.w);
  reinterpret_cast<u16x4*>(dst)[i] = o;
}

// all four 1024x1024 weights in one launch
__global__ __launch_bounds__(256) void cvt_w(const float* __restrict__ Wq,
                                             const float* __restrict__ Wk,
                                             const float* __restrict__ Wv,
                                             const float* __restrict__ Wo,
                                             u16* __restrict__ wbf, u16* __restrict__ wobf) {
  int blk = blockIdx.x;           // 0..4095
  int sel = blk >> 10;
  const float* src = (sel == 0) ? Wq : (sel == 1) ? Wk : (sel == 2) ? Wv : Wo;
  u16* dst = (sel < 3) ? (wbf + (size_t)sel * 1048576) : wobf;
  int i = (blk & 1023) * 256 + threadIdx.x;
  float4 v = reinterpret_cast<const float4*>(src)[i];
  u16x4 o;
  o.x = f2bf(v.x); o.y = f2bf(v.y); o.z = f2bf(v.z); o.w = f2bf(v.w);
  reinterpret_cast<u16x4*>(dst)[i] = o;
}

// ---------------- GEMM: C[m][n] = sum_k A[m][k] * B[n][k] (B^T input) ----------------
// 128x128 tile, BK=32, global_load_lds staging, chunk = 16 rows x 32 cols = 512 u16.
__device__ __forceinline__ void store_out(float* p, float v) { *p = v; }
__device__ __forceinline__ void store_out(u16* p, float v) { *p = f2bf(v); }

template <typename OutT>
__global__ __launch_bounds__(256) void gemm_bt(const u16* __restrict__ A,
                                               const u16* __restrict__ Bw,
                                               OutT* __restrict__ C, int N, int K) {
  __shared__ u16 As[4096];
  __shared__ u16 Bs[4096];
  const int tid = threadIdx.x;
  const int lane = tid & 63;
  const int wave = tid >> 6;
  const int wm = wave >> 1, wn = wave & 1;
  const int lh = lane & 15, quad = lane >> 4;
  const int q8 = quad * 8;
  const int m0 = blockIdx.y * 128, n0 = blockIdx.x * 128;

  f32x4 acc[4][4];
#pragma unroll
  for (int i = 0; i < 4; ++i)
#pragma unroll
    for (int j = 0; j < 4; ++j) { acc[i][j][0] = 0.f; acc[i][j][1] = 0.f; acc[i][j][2] = 0.f; acc[i][j][3] = 0.f; }

  const int nkt = K >> 5;
  for (int kt = 0; kt < nkt; ++kt) {
    const int kb = kt * 32;
    __syncthreads();  // prior tile's LDS reads done
#pragma unroll
    for (int i = 0; i < 4; ++i) {
      const int c = wave * 4 + i;  // 0..15 : 0-7 = A chunks, 8-15 = B chunks
      if (c < 8) {
        gload_lds16(A + (size_t)(m0 + c * 16 + lh) * K + kb + q8, &As[c * 512 + lane * 8]);
      } else {
        const int rb = c - 8;
        gload_lds16(Bw + (size_t)(n0 + rb * 16 + lh) * K + kb + q8, &Bs[rb * 512 + lane * 8]);
      }
    }
    __syncthreads();  // drains DMA, staged tile visible
    s16x8 af[4], bf4[4];
#pragma unroll
    for (int mb = 0; mb < 4; ++mb)
      af[mb] = *reinterpret_cast<const s16x8*>(&As[(wm * 4 + mb) * 512 + lane * 8]);
#pragma unroll
    for (int nb = 0; nb < 4; ++nb)
      bf4[nb] = *reinterpret_cast<const s16x8*>(&Bs[(wn * 4 + nb) * 512 + lane * 8]);
#pragma unroll
    for (int mb = 0; mb < 4; ++mb)
#pragma unroll
      for (int nb = 0; nb < 4; ++nb)
        acc[mb][nb] = __builtin_amdgcn_mfma_f32_16x16x32_bf16(af[mb], bf4[nb], acc[mb][nb], 0, 0, 0);
  }
#pragma unroll
  for (int mb = 0; mb < 4; ++mb)
#pragma unroll
    for (int nb = 0; nb < 4; ++nb) {
      const int col = n0 + wn * 64 + nb * 16 + lh;
#pragma unroll
      for (int r = 0; r < 4; ++r) {
        const int row = m0 + wm * 64 + mb * 16 + quad * 4 + r;
        store_out(&C[(size_t)row * N + col], acc[mb][nb][r]);
      }
    }
}

// ---------------- RoPE + pre-scale: raw QKV -> Qs(q/8), Q2s(0.0125 q^2), K, K^2 ----------------
__global__ __launch_bounds__(256) void rope_kernel(const u16* __restrict__ raw,
                                                   u16* __restrict__ Qs, u16* __restrict__ Q2s,
                                                   u16* __restrict__ Kb, u16* __restrict__ K2b) {
  int idx = blockIdx.x * 256 + threadIdx.x;  // 0 .. 4194303
  int which = idx >> 21;                     // 0 = Q, 1 = K
  int id = idx & 0x1FFFFF;
  int d = id & 31;
  int s = (id >> 5) & 2047;
  int bh = id >> 16;                         // b*16 + h
  int b = bh >> 4;
  int h = bh & 15;
  const u16* r = raw + (size_t)(b * 2048 + s) * 3072 + which * 1024 + h * 64 + d;
  float v1 = bf2f(r[0]);
  float v2 = bf2f(r[32]);
  float invf = __expf((float)d * -0.2878231366f);  // 10000^(-d/32)
  float ang = (float)s * invf;
  float sv, cv;
  __sincosf(ang, &sv, &cv);
  float e0 = v1 * cv - v2 * sv;
  float e1 = v2 * cv + v1 * sv;
  size_t ofs = (size_t)(bh * 2048 + s) * 64 + d;
  if (which == 0) {
    Qs[ofs]       = f2bf(e0 * 0.125f);
    Qs[ofs + 32]  = f2bf(e1 * 0.125f);
    Q2s[ofs]      = f2bf(e0 * e0 * 0.0125f);
    Q2s[ofs + 32] = f2bf(e1 * e1 * 0.0125f);
  } else {
    Kb[ofs]       = f2bf(e0);
    Kb[ofs + 32]  = f2bf(e1);
    K2b[ofs]      = f2bf(e0 * e0);
    K2b[ofs + 32] = f2bf(e1 * e1);
  }
}

// ---------------- V transpose: raw V cols -> Vt (B,H,64,S) bf16 ----------------
__global__ __launch_bounds__(256) void transpose_v(const u16* __restrict__ raw,
                                                   u16* __restrict__ Vt) {
  int st = blockIdx.x, bh = blockIdx.y;
  int b = bh >> 4, h = bh & 15;
  __shared__ u16 tile[64 * 72];
  int tid = threadIdx.x;
#pragma unroll
  for (int it = 0; it < 4; ++it) {
    int c = it * 256 + tid;
    int sr = c >> 4, d4 = c & 15;
    u16x4 v = *reinterpret_cast<const u16x4*>(
        raw + (size_t)(b * 2048 + st * 64 + sr) * 3072 + 2048 + h * 64 + d4 * 4);
    *reinterpret_cast<u16x4*>(&tile[sr * 72 + d4 * 4]) = v;
  }
  __syncthreads();
#pragma unroll
  for (int it = 0; it < 4; ++it) {
    int c = it * 256 + tid;
    int dd = c >> 4, s4 = c & 15;
    u16x4 v;
#pragma unroll
    for (int j = 0; j < 4; ++j) v[j] = tile[(s4 * 4 + j) * 72 + dd];
    *reinterpret_cast<u16x4*>(Vt + (size_t)(bh * 64 + dd) * 2048 + st * 64 + s4 * 4) = v;
  }
}

// ---------------- flash-style causal amplified attention, fixed-max softmax ----------------
// Q-tile 128 rows/block (4 waves x 32 rows, 2 m-blocks each); K-tile 64 keys.
// softmax max fixed at 8.0 (scores analytically << 8); shift-invariance makes the
// result exact, and the -8 bias is folded into the MFMA accumulator init.
// grid (16, 32), qi = 15 - bx (big blocks dispatch first).
__global__ __launch_bounds__(256, 2) void attn_kernel(const u16* __restrict__ Qs,
                                                      const u16* __restrict__ Q2s,
                                                      const u16* __restrict__ Kb,
                                                      const u16* __restrict__ K2b,
                                                      const u16* __restrict__ Vt,
                                                      const float* __restrict__ gate,
                                                      u16* __restrict__ attn) {
  const int qi = 15 - (int)blockIdx.x;
  const int bh = blockIdx.y;
  const int tid = threadIdx.x, lane = tid & 63, wave = tid >> 6;
  const int lh = lane & 15, quad = lane >> 4;
  const int b = bh >> 4, h = bh & 15;
  __shared__ u16 stageS[2][8192];   // [K chunks: 0..4095 | K2 chunks: 4096..8191], 512 u16/chunk
  __shared__ u16 Pbuf[4][2][1152];  // per (wave, mb): 16 rows x 72
  const int base = qi * 128 + wave * 32;   // wave's first Q row
  const int q8 = quad * 8;

  auto do_stage = [&](int buf, int kt) {
#pragma unroll
    for (int i = 0; i < 4; ++i) {
      const int c = wave * 4 + i;   // 0..15; t=c>>3 (0=K,1=K2), f=c&7 = kk*4+nb
      const int t = c >> 3, f = c & 7, kk = f >> 2, nb = f & 3;
      const u16* src = (t ? K2b : Kb) +
          (size_t)(bh * 2048 + kt * 64 + nb * 16 + lh) * 64 + kk * 32 + q8;
      gload_lds16(src, &stageS[buf][t * 4096 + f * 512 + lane * 8]);
    }
  };

  // Q fragments (A-layout): m = lh, k = kk*32 + quad*8 + j ; pre-scaled in memory
  s16x8 qf[2][2], q2f[2][2];
#pragma unroll
  for (int mb = 0; mb < 2; ++mb) {
    const size_t qoff = (size_t)(bh * 2048 + base + mb * 16 + lh) * 64 + q8;
#pragma unroll
    for (int kk = 0; kk < 2; ++kk) {
      qf[mb][kk]  = *reinterpret_cast<const s16x8*>(Qs + qoff + kk * 32);
      q2f[mb][kk] = *reinterpret_cast<const s16x8*>(Q2s + qoff + kk * 32);
    }
  }

  f32x4 oacc[2][4];
  float lsum[2][4];
#pragma unroll
  for (int mb = 0; mb < 2; ++mb)
#pragma unroll
    for (int nb = 0; nb < 4; ++nb) { oacc[mb][nb][0] = 0.f; oacc[mb][nb][1] = 0.f; oacc[mb][nb][2] = 0.f; oacc[mb][nb][3] = 0.f; }
#pragma unroll
  for (int mb = 0; mb < 2; ++mb)
#pragma unroll
    for (int r = 0; r < 4; ++r) lsum[mb][r] = 0.f;
  float gw[4];
#pragma unroll
  for (int nb = 0; nb < 4; ++nb) gw[nb] = gate[nb * 16 + lh];

  do_stage(0, 0);
  __syncthreads();  // drain DMA for tile 0

  const int ktmax = 2 * qi + 1;
  const int wmaxrow = base + 31;
  for (int kt = 0; kt <= ktmax; ++kt) {
    const int p = kt & 1;
    if (kt < ktmax) do_stage(1 - p, kt + 1);  // async prefetch, drained at end barrier

    if (kt * 64 <= wmaxrow) {  // wave-uniform skip of fully-masked tiles
      const u16* Ks = stageS[p];
      f32x4 sacc[2][4];
#pragma unroll
      for (int mb = 0; mb < 2; ++mb)
#pragma unroll
        for (int nb = 0; nb < 4; ++nb) { sacc[mb][nb][0] = -8.f; sacc[mb][nb][1] = -8.f; sacc[mb][nb][2] = -8.f; sacc[mb][nb][3] = -8.f; }
#pragma unroll
      for (int nb = 0; nb < 4; ++nb)
#pragma unroll
        for (int kk = 0; kk < 2; ++kk) {
          s16x8 kf  = *reinterpret_cast<const s16x8*>(&Ks[(kk * 4 + nb) * 512 + lane * 8]);
          s16x8 k2f = *reinterpret_cast<const s16x8*>(&Ks[4096 + (kk * 4 + nb) * 512 + lane * 8]);
#pragma unroll
          for (int mb = 0; mb < 2; ++mb) {
            sacc[mb][nb] = __builtin_amdgcn_mfma_f32_16x16x32_bf16(qf[mb][kk],  kf,  sacc[mb][nb], 0, 0, 0);
            sacc[mb][nb] = __builtin_amdgcn_mfma_f32_16x16x32_bf16(q2f[mb][kk], k2f, sacc[mb][nb], 0, 0, 0);
          }
        }
      // V prefetch (global; latency hides under exp/pack)
      s16x8 vf[2][4];
#pragma unroll
      for (int kk = 0; kk < 2; ++kk)
#pragma unroll
        for (int nb = 0; nb < 4; ++nb)
          vf[kk][nb] = *reinterpret_cast<const s16x8*>(
              Vt + (size_t)(bh * 64 + nb * 16 + lh) * 2048 + kt * 64 + kk * 32 + q8);

      if (kt * 64 + 63 > base) {  // tiles overlapping the diagonal: elementwise mask
#pragma unroll
        for (int mb = 0; mb < 2; ++mb)
#pragma unroll
          for (int nb = 0; nb < 4; ++nb) {
            const int colg = kt * 64 + nb * 16 + lh;
#pragma unroll
            for (int r = 0; r < 4; ++r) {
              const int rowg = base + mb * 16 + quad * 4 + r;
              if (colg > rowg) sacc[mb][nb][r] = -1e9f;
            }
          }
      }
      // p = exp(s - 8); per-lane row-sum partials (reduced once after the loop)
#pragma unroll
      for (int mb = 0; mb < 2; ++mb)
#pragma unroll
        for (int nb = 0; nb < 4; ++nb)
#pragma unroll
          for (int r = 0; r < 4; ++r) {
            float pv = __expf(sacc[mb][nb][r]);
            lsum[mb][r] += pv;
            Pbuf[wave][mb][(quad * 4 + r) * 72 + nb * 16 + lh] = f2bf(pv);
          }
      // PV: P through LDS (C-layout -> A-layout), wave-private, no barrier
#pragma unroll
      for (int mb = 0; mb < 2; ++mb)
#pragma unroll
        for (int kk = 0; kk < 2; ++kk) {
          s16x8 pf = *reinterpret_cast<const s16x8*>(&Pbuf[wave][mb][lh * 72 + kk * 32 + q8]);
#pragma unroll
          for (int nb = 0; nb < 4; ++nb)
            oacc[mb][nb] = __builtin_amdgcn_mfma_f32_16x16x32_bf16(pf, vf[kk][nb], oacc[mb][nb], 0, 0, 0);
        }
    }
    __syncthreads();  // all waves done with stageS[p]; prefetch for kt+1 drained
  }
  // reduce row sums across the 16 lanes holding each row
#pragma unroll
  for (int mb = 0; mb < 2; ++mb)
#pragma unroll
    for (int r = 0; r < 4; ++r) {
      float rs = lsum[mb][r];
#pragma unroll
      for (int off = 1; off < 16; off <<= 1) rs += __shfl_xor(rs, off);
      lsum[mb][r] = 1.0f / rs;
    }
  // finalize: o/l, epilogue o + 0.05*o^2*g[d] (out2==out1 identity)
#pragma unroll
  for (int mb = 0; mb < 2; ++mb)
#pragma unroll
    for (int nb = 0; nb < 4; ++nb)
#pragma unroll
      for (int r = 0; r < 4; ++r) {
        float o = oacc[mb][nb][r] * lsum[mb][r];
        float val = o + 0.05f * o * o * gw[nb];
        const int rows = base + mb * 16 + quad * 4 + r;
        attn[(size_t)(b * 2048 + rows) * 1024 + h * 64 + nb * 16 + lh] = f2bf(val);
      }
}

extern "C" void kernel_launch(void* const* d_in, const int* in_sizes, int n_in,
                              void* d_out, int out_size, void* d_ws, size_t ws_size,
                              hipStream_t stream) {
  (void)in_sizes; (void)n_in; (void)out_size; (void)ws_size;
  const float* x    = (const float*)d_in[0];
  const float* Wq   = (const float*)d_in[1];
  const float* Wk   = (const float*)d_in[2];
  const float* Wv   = (const float*)d_in[3];
  const float* Wo   = (const float*)d_in[4];
  const float* gate = (const float*)d_in[5];

  u16* ws    = (u16*)d_ws;
  u16* xbf   = ws;                    // 4096x1024 (dead after QKV gemm)
  u16* wbf   = xbf + 4194304;         // 3072x1024 (Wq|Wk|Wv rows)
  u16* wobf  = wbf + 3145728;         // 1024x1024
  u16* raw   = wobf + 1048576;        // 4096x3072 QKV gemm out (dead after rope+transpose)
  u16* Qsb   = raw + 12582912;        // (B,H,S,64) q/8
  u16* Kbb   = Qsb + 4194304;         // (B,H,S,64)
  u16* K2bb  = Kbb + 4194304;         // (B,H,S,64)
  u16* Vtb   = K2bb + 4194304;        // (B,H,64,S)
  u16* Q2sb  = xbf;                   // alias: written by rope (after gemm)
  u16* attnb = raw;                   // alias: written by attn (after rope/transpose)

  cvt_kernel<<<4096, 256, 0, stream>>>(x, xbf, 1048576);
  cvt_w<<<4096, 256, 0, stream>>>(Wq, Wk, Wv, Wo, wbf, wobf);

  gemm_bt<u16><<<dim3(24, 32), 256, 0, stream>>>(xbf, wbf, raw, 3072, 1024);
  rope_kernel<<<16384, 256, 0, stream>>>(raw, Qsb, Q2sb, Kbb, K2bb);
  transpose_v<<<dim3(32, 32), 256, 0, stream>>>(raw, Vtb);
  attn_kernel<<<dim3(16, 32), 256, 0, stream>>>(Qsb, Q2sb, Kbb, K2bb, Vtb, gate, attnb);
  gemm_bt<float><<<dim3(8, 32), 256, 0, stream>>>(attnb, wobf, (float*)d_out, 1024, 1024);
}

// Round 6
// 268.295 us; speedup vs baseline: 1.5882x; 1.0214x over previous
//
#include <hip/hip_runtime.h>

typedef unsigned short u16;
typedef __attribute__((ext_vector_type(4))) unsigned short u16x4;
typedef __attribute__((ext_vector_type(8))) unsigned short u16x8;
typedef __attribute__((ext_vector_type(8))) short s16x8;
typedef __attribute__((ext_vector_type(4))) float f32x4;

__device__ __forceinline__ u16 f2bf(float f) {
  unsigned int u = __float_as_uint(f);
  u += 0x7FFFu + ((u >> 16) & 1u);   // RNE
  return (u16)(u >> 16);
}
__device__ __forceinline__ float bf2f(u16 h) {
  return __uint_as_float(((unsigned int)h) << 16);
}

// async global->LDS, 16B per lane; base = lane0's lds ptr, lane i writes base+i*16B.
__device__ __forceinline__ void gload_lds16(const u16* g, u16* l) {
  __builtin_amdgcn_global_load_lds(
      (const __attribute__((address_space(1))) unsigned int*)(g),
      (__attribute__((address_space(3))) unsigned int*)(l), 16, 0, 0);
}

// ---------------- fp32 -> bf16 convert (x4 vectorized) ----------------
__global__ __launch_bounds__(256) void cvt_kernel(const float* __restrict__ src,
                                                  u16* __restrict__ dst, int n4) {
  int i = blockIdx.x * 256 + threadIdx.x;
  if (i >= n4) return;
  float4 v = reinterpret_cast<const float4*>(src)[i];
  u16x4 o;
  o.x = f2bf(v.x); o.y = f2bf(v.y); o.z = f2bf(v.z); o.w = f2bf(v.w);
  reinterpret_cast<u16x4*>(dst)[i] = o;
}

// all four 1024x1024 weights in one launch
__global__ __launch_bounds__(256) void cvt_w(const float* __restrict__ Wq,
                                             const float* __restrict__ Wk,
                                             const float* __restrict__ Wv,
                                             const float* __restrict__ Wo,
                                             u16* __restrict__ wbf, u16* __restrict__ wobf) {
  int blk = blockIdx.x;           // 0..4095
  int sel = blk >> 10;
  const float* src = (sel == 0) ? Wq : (sel == 1) ? Wk : (sel == 2) ? Wv : Wo;
  u16* dst = (sel < 3) ? (wbf + (size_t)sel * 1048576) : wobf;
  int i = (blk & 1023) * 256 + threadIdx.x;
  float4 v = reinterpret_cast<const float4*>(src)[i];
  u16x4 o;
  o.x = f2bf(v.x); o.y = f2bf(v.y); o.z = f2bf(v.z); o.w = f2bf(v.w);
  reinterpret_cast<u16x4*>(dst)[i] = o;
}

// ---------------- GEMM: C[m][n] = sum_k A[m][k] * B[n][k] (B^T input) ----------------
// 128x128 tile, BK=32, global_load_lds staging, chunk = 16 rows x 32 cols = 512 u16.
__device__ __forceinline__ void store_out(float* p, float v) { *p = v; }
__device__ __forceinline__ void store_out(u16* p, float v) { *p = f2bf(v); }

template <typename OutT>
__global__ __launch_bounds__(256) void gemm_bt(const u16* __restrict__ A,
                                               const u16* __restrict__ Bw,
                                               OutT* __restrict__ C, int N, int K) {
  __shared__ u16 As[4096];
  __shared__ u16 Bs[4096];
  const int tid = threadIdx.x;
  const int lane = tid & 63;
  const int wave = tid >> 6;
  const int wm = wave >> 1, wn = wave & 1;
  const int lh = lane & 15, quad = lane >> 4;
  const int q8 = quad * 8;
  const int m0 = blockIdx.y * 128, n0 = blockIdx.x * 128;

  f32x4 acc[4][4];
#pragma unroll
  for (int i = 0; i < 4; ++i)
#pragma unroll
    for (int j = 0; j < 4; ++j) { acc[i][j][0] = 0.f; acc[i][j][1] = 0.f; acc[i][j][2] = 0.f; acc[i][j][3] = 0.f; }

  const int nkt = K >> 5;
  for (int kt = 0; kt < nkt; ++kt) {
    const int kb = kt * 32;
    __syncthreads();  // prior tile's LDS reads done
#pragma unroll
    for (int i = 0; i < 4; ++i) {
      const int c = wave * 4 + i;  // 0..15 : 0-7 = A chunks, 8-15 = B chunks
      if (c < 8) {
        gload_lds16(A + (size_t)(m0 + c * 16 + lh) * K + kb + q8, &As[c * 512 + lane * 8]);
      } else {
        const int rb = c - 8;
        gload_lds16(Bw + (size_t)(n0 + rb * 16 + lh) * K + kb + q8, &Bs[rb * 512 + lane * 8]);
      }
    }
    __syncthreads();  // drains DMA, staged tile visible
    s16x8 af[4], bf4[4];
#pragma unroll
    for (int mb = 0; mb < 4; ++mb)
      af[mb] = *reinterpret_cast<const s16x8*>(&As[(wm * 4 + mb) * 512 + lane * 8]);
#pragma unroll
    for (int nb = 0; nb < 4; ++nb)
      bf4[nb] = *reinterpret_cast<const s16x8*>(&Bs[(wn * 4 + nb) * 512 + lane * 8]);
#pragma unroll
    for (int mb = 0; mb < 4; ++mb)
#pragma unroll
      for (int nb = 0; nb < 4; ++nb)
        acc[mb][nb] = __builtin_amdgcn_mfma_f32_16x16x32_bf16(af[mb], bf4[nb], acc[mb][nb], 0, 0, 0);
  }
#pragma unroll
  for (int mb = 0; mb < 4; ++mb)
#pragma unroll
    for (int nb = 0; nb < 4; ++nb) {
      const int col = n0 + wn * 64 + nb * 16 + lh;
#pragma unroll
      for (int r = 0; r < 4; ++r) {
        const int row = m0 + wm * 64 + mb * 16 + quad * 4 + r;
        store_out(&C[(size_t)row * N + col], acc[mb][nb][r]);
      }
    }
}

// ---------------- RoPE + pre-scale: raw QKV -> Qs(q/8), Q2s(0.0125 q^2), K, K^2 ----------------
__global__ __launch_bounds__(256) void rope_kernel(const u16* __restrict__ raw,
                                                   u16* __restrict__ Qs, u16* __restrict__ Q2s,
                                                   u16* __restrict__ Kb, u16* __restrict__ K2b) {
  int idx = blockIdx.x * 256 + threadIdx.x;  // 0 .. 4194303
  int which = idx >> 21;                     // 0 = Q, 1 = K
  int id = idx & 0x1FFFFF;
  int d = id & 31;
  int s = (id >> 5) & 2047;
  int bh = id >> 16;                         // b*16 + h
  int b = bh >> 4;
  int h = bh & 15;
  const u16* r = raw + (size_t)(b * 2048 + s) * 3072 + which * 1024 + h * 64 + d;
  float v1 = bf2f(r[0]);
  float v2 = bf2f(r[32]);
  float invf = __expf((float)d * -0.2878231366f);  // 10000^(-d/32)
  float ang = (float)s * invf;
  float sv, cv;
  __sincosf(ang, &sv, &cv);
  float e0 = v1 * cv - v2 * sv;
  float e1 = v2 * cv + v1 * sv;
  size_t ofs = (size_t)(bh * 2048 + s) * 64 + d;
  if (which == 0) {
    Qs[ofs]       = f2bf(e0 * 0.125f);
    Qs[ofs + 32]  = f2bf(e1 * 0.125f);
    Q2s[ofs]      = f2bf(e0 * e0 * 0.0125f);
    Q2s[ofs + 32] = f2bf(e1 * e1 * 0.0125f);
  } else {
    Kb[ofs]       = f2bf(e0);
    Kb[ofs + 32]  = f2bf(e1);
    K2b[ofs]      = f2bf(e0 * e0);
    K2b[ofs + 32] = f2bf(e1 * e1);
  }
}

// ---------------- V transpose: raw V cols -> Vt (B,H,64,S) bf16 ----------------
__global__ __launch_bounds__(256) void transpose_v(const u16* __restrict__ raw,
                                                   u16* __restrict__ Vt) {
  int st = blockIdx.x, bh = blockIdx.y;
  int b = bh >> 4, h = bh & 15;
  __shared__ u16 tile[64 * 72];
  int tid = threadIdx.x;
#pragma unroll
  for (int it = 0; it < 4; ++it) {
    int c = it * 256 + tid;
    int sr = c >> 4, d4 = c & 15;
    u16x4 v = *reinterpret_cast<const u16x4*>(
        raw + (size_t)(b * 2048 + st * 64 + sr) * 3072 + 2048 + h * 64 + d4 * 4);
    *reinterpret_cast<u16x4*>(&tile[sr * 72 + d4 * 4]) = v;
  }
  __syncthreads();
#pragma unroll
  for (int it = 0; it < 4; ++it) {
    int c = it * 256 + tid;
    int dd = c >> 4, s4 = c & 15;
    u16x4 v;
#pragma unroll
    for (int j = 0; j < 4; ++j) v[j] = tile[(s4 * 4 + j) * 72 + dd];
    *reinterpret_cast<u16x4*>(Vt + (size_t)(bh * 64 + dd) * 2048 + st * 64 + s4 * 4) = v;
  }
}

// ---------------- flash-style causal amplified attention, fixed-max + split-K ----------------
// Q-tile 128 rows/block (4 waves x 32 rows). Fixed softmax max 8 => partial
// (O, l) over disjoint key ranges are directly addable. qi>=8 blocks split the
// kt range in two (partials to ws, fp32); qi<8 blocks finalize inline.
// grid (24, 32): bx = 3g+t, t in {0,1}: qi=15-g half t; t==2: qi=7-g whole.
__global__ __launch_bounds__(256, 2) void attn_kernel(const u16* __restrict__ Qs,
                                                      const u16* __restrict__ Q2s,
                                                      const u16* __restrict__ Kb,
                                                      const u16* __restrict__ K2b,
                                                      const u16* __restrict__ Vt,
                                                      const float* __restrict__ gate,
                                                      u16* __restrict__ attn,
                                                      float* __restrict__ Opart,
                                                      float* __restrict__ Lpart) {
  const int bx = blockIdx.x;
  const int g = bx / 3, t = bx - 3 * g;
  int qi, kt0, kt1, half;
  bool split;
  if (t < 2) { qi = 15 - g; split = true;  half = t; const int nk = qi + 1; kt0 = t * nk; kt1 = kt0 + nk - 1; }
  else       { qi = 7 - g;  split = false; half = 0; kt0 = 0; kt1 = 2 * qi + 1; }
  const int bh = blockIdx.y;
  const int tid = threadIdx.x, lane = tid & 63, wave = tid >> 6;
  const int lh = lane & 15, quad = lane >> 4;
  const int b = bh >> 4, h = bh & 15;
  __shared__ u16 stageS[2][8192];   // [K chunks: 0..4095 | K2 chunks: 4096..8191], 512 u16/chunk
  __shared__ u16 Pbuf[4][2][1152];  // per (wave, mb): 16 rows x 72
  const int base = qi * 128 + wave * 32;   // wave's first Q row
  const int q8 = quad * 8;

  auto do_stage = [&](int buf, int kt) {
#pragma unroll
    for (int i = 0; i < 4; ++i) {
      const int c = wave * 4 + i;   // 0..15; t2=c>>3 (0=K,1=K2), f=c&7 = kk*4+nb
      const int t2 = c >> 3, f = c & 7, kk = f >> 2, nb = f & 3;
      const u16* src = (t2 ? K2b : Kb) +
          (size_t)(bh * 2048 + kt * 64 + nb * 16 + lh) * 64 + kk * 32 + q8;
      gload_lds16(src, &stageS[buf][t2 * 4096 + f * 512 + lane * 8]);
    }
  };

  // Q fragments (A-layout): m = lh, k = kk*32 + quad*8 + j ; pre-scaled in memory
  s16x8 qf[2][2], q2f[2][2];
#pragma unroll
  for (int mb = 0; mb < 2; ++mb) {
    const size_t qoff = (size_t)(bh * 2048 + base + mb * 16 + lh) * 64 + q8;
#pragma unroll
    for (int kk = 0; kk < 2; ++kk) {
      qf[mb][kk]  = *reinterpret_cast<const s16x8*>(Qs + qoff + kk * 32);
      q2f[mb][kk] = *reinterpret_cast<const s16x8*>(Q2s + qoff + kk * 32);
    }
  }

  f32x4 oacc[2][4];
  float lsum[2][4];
#pragma unroll
  for (int mb = 0; mb < 2; ++mb)
#pragma unroll
    for (int nb = 0; nb < 4; ++nb) { oacc[mb][nb][0] = 0.f; oacc[mb][nb][1] = 0.f; oacc[mb][nb][2] = 0.f; oacc[mb][nb][3] = 0.f; }
#pragma unroll
  for (int mb = 0; mb < 2; ++mb)
#pragma unroll
    for (int r = 0; r < 4; ++r) lsum[mb][r] = 0.f;
  float gw[4];
#pragma unroll
  for (int nb = 0; nb < 4; ++nb) gw[nb] = gate[nb * 16 + lh];

  do_stage(0, kt0);
  __syncthreads();  // drain DMA for first tile

  const int wmaxrow = base + 31;
  for (int kt = kt0; kt <= kt1; ++kt) {
    const int p = (kt - kt0) & 1;
    if (kt < kt1) do_stage(1 - p, kt + 1);  // async prefetch, drained at end barrier

    if (kt * 64 <= wmaxrow) {  // wave-uniform skip of fully-masked tiles
      const u16* Ks = stageS[p];
      f32x4 sacc[2][4];
#pragma unroll
      for (int mb = 0; mb < 2; ++mb)
#pragma unroll
        for (int nb = 0; nb < 4; ++nb) { sacc[mb][nb][0] = -8.f; sacc[mb][nb][1] = -8.f; sacc[mb][nb][2] = -8.f; sacc[mb][nb][3] = -8.f; }
#pragma unroll
      for (int nb = 0; nb < 4; ++nb)
#pragma unroll
        for (int kk = 0; kk < 2; ++kk) {
          s16x8 kf  = *reinterpret_cast<const s16x8*>(&Ks[(kk * 4 + nb) * 512 + lane * 8]);
          s16x8 k2f = *reinterpret_cast<const s16x8*>(&Ks[4096 + (kk * 4 + nb) * 512 + lane * 8]);
#pragma unroll
          for (int mb = 0; mb < 2; ++mb) {
            sacc[mb][nb] = __builtin_amdgcn_mfma_f32_16x16x32_bf16(qf[mb][kk],  kf,  sacc[mb][nb], 0, 0, 0);
            sacc[mb][nb] = __builtin_amdgcn_mfma_f32_16x16x32_bf16(q2f[mb][kk], k2f, sacc[mb][nb], 0, 0, 0);
          }
        }
      // V prefetch (global; latency hides under exp/pack)
      s16x8 vf[2][4];
#pragma unroll
      for (int kk = 0; kk < 2; ++kk)
#pragma unroll
        for (int nb = 0; nb < 4; ++nb)
          vf[kk][nb] = *reinterpret_cast<const s16x8*>(
              Vt + (size_t)(bh * 64 + nb * 16 + lh) * 2048 + kt * 64 + kk * 32 + q8);

      if (kt * 64 + 63 > base) {  // tiles overlapping the diagonal: elementwise mask
#pragma unroll
        for (int mb = 0; mb < 2; ++mb)
#pragma unroll
          for (int nb = 0; nb < 4; ++nb) {
            const int colg = kt * 64 + nb * 16 + lh;
#pragma unroll
            for (int r = 0; r < 4; ++r) {
              const int rowg = base + mb * 16 + quad * 4 + r;
              if (colg > rowg) sacc[mb][nb][r] = -1e9f;
            }
          }
      }
      // p = exp(s - 8); per-lane row-sum partials (reduced once after the loop)
#pragma unroll
      for (int mb = 0; mb < 2; ++mb)
#pragma unroll
        for (int nb = 0; nb < 4; ++nb)
#pragma unroll
          for (int r = 0; r < 4; ++r) {
            float pv = __expf(sacc[mb][nb][r]);
            lsum[mb][r] += pv;
            Pbuf[wave][mb][(quad * 4 + r) * 72 + nb * 16 + lh] = f2bf(pv);
          }
      // PV: P through LDS (C-layout -> A-layout), wave-private, no barrier
#pragma unroll
      for (int mb = 0; mb < 2; ++mb)
#pragma unroll
        for (int kk = 0; kk < 2; ++kk) {
          s16x8 pf = *reinterpret_cast<const s16x8*>(&Pbuf[wave][mb][lh * 72 + kk * 32 + q8]);
#pragma unroll
          for (int nb = 0; nb < 4; ++nb)
            oacc[mb][nb] = __builtin_amdgcn_mfma_f32_16x16x32_bf16(pf, vf[kk][nb], oacc[mb][nb], 0, 0, 0);
        }
    }
    __syncthreads();  // all waves done with stageS[p]; prefetch for kt+1 drained
  }
  // reduce row sums across the 16 lanes holding each row
#pragma unroll
  for (int mb = 0; mb < 2; ++mb)
#pragma unroll
    for (int r = 0; r < 4; ++r) {
      float rs = lsum[mb][r];
#pragma unroll
      for (int off = 1; off < 16; off <<= 1) rs += __shfl_xor(rs, off);
      lsum[mb][r] = rs;
    }
  if (split) {
    // unnormalized partials to ws (fp32); rows are base..base+31 (all >= 1024)
#pragma unroll
    for (int mb = 0; mb < 2; ++mb)
#pragma unroll
      for (int r = 0; r < 4; ++r) {
        const int rowRel = base + mb * 16 + quad * 4 + r - 1024;
        const size_t orow = ((size_t)half * 32768 + bh * 1024 + rowRel);
        if (lh == 0) Lpart[orow] = lsum[mb][r];
#pragma unroll
        for (int nb = 0; nb < 4; ++nb)
          Opart[orow * 64 + nb * 16 + lh] = oacc[mb][nb][r];
      }
  } else {
    // finalize: o/l, epilogue o + 0.05*o^2*g[d] (out2==out1 identity)
#pragma unroll
    for (int mb = 0; mb < 2; ++mb)
#pragma unroll
      for (int r = 0; r < 4; ++r) {
        const float invl = 1.0f / lsum[mb][r];
        const int rows = base + mb * 16 + quad * 4 + r;
#pragma unroll
        for (int nb = 0; nb < 4; ++nb) {
          float o = oacc[mb][nb][r] * invl;
          float val = o + 0.05f * o * o * gw[nb];
          attn[(size_t)(b * 2048 + rows) * 1024 + h * 64 + nb * 16 + lh] = f2bf(val);
        }
      }
  }
}

// ---------------- combine split-K partials (rows s >= 1024) ----------------
__global__ __launch_bounds__(256) void combine_kernel(const float* __restrict__ Opart,
                                                      const float* __restrict__ Lpart,
                                                      const float* __restrict__ gate,
                                                      u16* __restrict__ attn) {
  int idx = blockIdx.x * 256 + threadIdx.x;   // 0 .. 2097151
  int d = idx & 63;
  int rowi = idx >> 6;                        // bh*1024 + rowRel
  int bh = rowi >> 10, rr = rowi & 1023;
  float o = Opart[idx] + Opart[idx + 2097152];
  float l = Lpart[rowi] + Lpart[rowi + 32768];
  o /= l;
  float val = o + 0.05f * o * o * gate[d];
  int b = bh >> 4, h = bh & 15;
  int s = 1024 + rr;
  attn[(size_t)(b * 2048 + s) * 1024 + h * 64 + d] = f2bf(val);
}

extern "C" void kernel_launch(void* const* d_in, const int* in_sizes, int n_in,
                              void* d_out, int out_size, void* d_ws, size_t ws_size,
                              hipStream_t stream) {
  (void)in_sizes; (void)n_in; (void)out_size; (void)ws_size;
  const float* x    = (const float*)d_in[0];
  const float* Wq   = (const float*)d_in[1];
  const float* Wk   = (const float*)d_in[2];
  const float* Wv   = (const float*)d_in[3];
  const float* Wo   = (const float*)d_in[4];
  const float* gate = (const float*)d_in[5];

  u16* ws    = (u16*)d_ws;
  u16* xbf   = ws;                    // 4096x1024 (dead after QKV gemm)
  u16* wbf   = xbf + 4194304;         // 3072x1024 (Wq|Wk|Wv rows)
  u16* wobf  = wbf + 3145728;         // 1024x1024
  u16* raw   = wobf + 1048576;        // 4096x3072 QKV gemm out (dead after rope+transpose)
  u16* Qsb   = raw + 12582912;        // (B,H,S,64) q/8
  u16* Kbb   = Qsb + 4194304;         // (B,H,S,64)
  u16* K2bb  = Kbb + 4194304;         // (B,H,S,64)
  u16* Vtb   = K2bb + 4194304;        // (B,H,64,S)
  float* Opart = (float*)(Vtb + 4194304);  // 2 x 32 x 1024 x 64 fp32 (16 MB)
  float* Lpart = Opart + 4194304;          // 2 x 32 x 1024 fp32 (256 KB)
  u16* Q2sb  = xbf;                   // alias: written by rope (after gemm)
  u16* attnb = raw;                   // alias: written by attn (after rope/transpose)

  cvt_kernel<<<4096, 256, 0, stream>>>(x, xbf, 1048576);
  cvt_w<<<4096, 256, 0, stream>>>(Wq, Wk, Wv, Wo, wbf, wobf);

  gemm_bt<u16><<<dim3(24, 32), 256, 0, stream>>>(xbf, wbf, raw, 3072, 1024);
  rope_kernel<<<16384, 256, 0, stream>>>(raw, Qsb, Q2sb, Kbb, K2bb);
  transpose_v<<<dim3(32, 32), 256, 0, stream>>>(raw, Vtb);
  attn_kernel<<<dim3(24, 32), 256, 0, stream>>>(Qsb, Q2sb, Kbb, K2bb, Vtb, gate, attnb,
                                                Opart, Lpart);
  combine_kernel<<<8192, 256, 0, stream>>>(Opart, Lpart, gate, attnb);
  gemm_bt<float><<<dim3(8, 32), 256, 0, stream>>>(attnb, wobf, (float*)d_out, 1024, 1024);
}